// Round 6
// baseline (348.350 us; speedup 1.0000x reference)
//
#include <hip/hip_runtime.h>

typedef _Float16 half_t;
typedef _Float16 half4 __attribute__((ext_vector_type(4)));
typedef _Float16 half8 __attribute__((ext_vector_type(8)));
typedef float floatx4 __attribute__((ext_vector_type(4)));

#define B_ 32
#define T_ 512
#define H_ 256
#define L_ 2048

// ------------------------------------------------------------------
// Fused setup: blocks [0,128) = meta (scan/searchsorted/bucket idx),
// blocks [128,512) = weight prep fp32 -> f16, CHUNK-CONTIGUOUS layout:
//   chunk c = (pred*4+layer)*16 + nt   (8 KB each, linear for LDS DMA)
//   within chunk: halves [kk*512 + lane*8 .. +7] hold
//   W[kk*32 + (lane>>4)*8 + j][nt*16 + (lane&15)]
// ------------------------------------------------------------------
__global__ __launch_bounds__(256) void setup_kernel(
    const int* __restrict__ dur,
    const float* __restrict__ pitch_t,
    const float* __restrict__ energy_t,
    const float* __restrict__ dur_W,
    const float* __restrict__ pit_W,
    const float* __restrict__ en_W,
    half_t* __restrict__ Wp,
    int* __restrict__ idx_ws,
    int* __restrict__ pi_ws,
    int* __restrict__ ei_ws,
    int* __restrict__ ml_ws,
    float* __restrict__ out4,
    float* __restrict__ out5) {
  __shared__ int cum_l[T_];
  __shared__ int ml_s;
  int bid = blockIdx.x;
  int tid = threadIdx.x;

  if (bid >= 128) {
    // ---- weight prep ----
    int g = (bid - 128) * 256 + tid;          // [0, 98304)
    int lane = g & 63;
    int t = g >> 6;                            // [0, 1536)
    int nt = t & 15;
    int kk = (t >> 4) & 7;
    int layer = (t >> 7) & 3;
    int pred = t >> 9;
    const float* W = (pred == 0 ? dur_W : (pred == 1 ? pit_W : en_W)) + layer * 65536;
    int n = nt * 16 + (lane & 15);
    int k0 = kk * 32 + (lane >> 4) * 8;
    half8 o;
#pragma unroll
    for (int j = 0; j < 8; ++j) o[j] = (half_t)W[(k0 + j) * 256 + n];
    int c = (pred * 4 + layer) * 16 + nt;
    *(half8*)&Wp[(size_t)c * 4096 + kk * 512 + lane * 8] = o;
    return;
  }

  // ---- meta ----
  int b = bid >> 2;
  int chunk = bid & 3;
  if (tid < 64) {
    int l = tid;
    const int* dr = dur + b * T_;
    int v[8];
    int base = l * 8;
#pragma unroll
    for (int j = 0; j < 8; ++j) v[j] = dr[base + j];
#pragma unroll
    for (int j = 1; j < 8; ++j) v[j] += v[j - 1];
    int tot = v[7];
    int inc = tot;
    for (int d = 1; d < 64; d <<= 1) {
      int t = __shfl_up(inc, d);
      if (l >= d) inc += t;
    }
    int excl = inc - tot;
#pragma unroll
    for (int j = 0; j < 8; ++j) cum_l[base + j] = excl + v[j];
    if (l == 63) {
      int mel = min(inc, L_);
      ml_s = mel;
      if (chunk == 0) {
        ml_ws[b] = mel;
        out4[b] = (float)mel;
      }
    }
  }
  __syncthreads();
  int ml = ml_s;
#pragma unroll
  for (int j = 0; j < 2; ++j) {
    int m = chunk * 512 + j * 256 + tid;
    int lo = 0;
#pragma unroll
    for (int sh = 8; sh >= 0; --sh) {
      int c = lo + (1 << sh);
      if (c <= T_ && cum_l[c - 1] <= m) lo = c;
    }
    int idx = min(lo, T_ - 1);
    int g = b * L_ + m;
    idx_ws[g] = idx;
    pi_ws[g] = (int)ceilf(pitch_t[g] * 256.0f);
    ei_ws[g] = (int)ceilf(energy_t[g] * 256.0f);
    out5[g] = (m >= ml) ? 1.0f : 0.0f;
  }
}

// ------------------------------------------------------------------
// Fused 4-layer MLP + head.
// blocks [0,1024): pitch  [1024,2048): energy  [2048,2304): duration.
// Block = 128 threads (2 waves) / 64 rows; wave owns 32 rows
// EXCLUSIVELY (h wave-private in LDS -> no h barriers).
// Weights: ONE LDS copy per 8 KB chunk shared by both waves, staged
// via global_load_lds (zero VGPR), 3-buffer ring, DISTANCE-2 prefetch,
// counted s_waitcnt vmcnt(4) + raw s_barrier (never vmcnt(0) in loop).
// Per chunk: 8 ds_read_b128 (1 KB contiguous each, conflict-free) +
// 16 MFMA in 4 independent 4-deep chains + epilogue.
// h layout [kk][64][32] halves: hf reloads 1024B-contiguous.
// Head fused into layer-3 epilogue (f32 partials + shfl reduce).
// LDS 32 KB (h) + 24 KB (w ring) = 56 KB -> 2 blocks/CU.
// Pitch-mode staging also emits out0 = xe + pemb + eemb (fused).
// ------------------------------------------------------------------
__device__ __forceinline__ void stage16(const void* g, void* l) {
  __builtin_amdgcn_global_load_lds(
      (const __attribute__((address_space(1))) void*)g,
      (__attribute__((address_space(3))) void*)l, 16, 0, 0);
}

__global__ __launch_bounds__(128, 1) void predictor_kernel(
    const float* __restrict__ x,
    const half_t* __restrict__ Wp,
    const float* __restrict__ dur_b, const float* __restrict__ dur_w, const float* __restrict__ dur_b2,
    const float* __restrict__ pit_b, const float* __restrict__ pit_w, const float* __restrict__ pit_b2,
    const float* __restrict__ en_b,  const float* __restrict__ en_w,  const float* __restrict__ en_b2,
    const int* __restrict__ idx_ws, const int* __restrict__ pi_ws, const int* __restrict__ ei_ws,
    const int* __restrict__ mlw,
    const float* __restrict__ src_seq, const unsigned char* __restrict__ src_mask,
    const float* __restrict__ pemb, const float* __restrict__ eemb,
    float* __restrict__ out0, float* __restrict__ out1,
    float* __restrict__ out2, float* __restrict__ out3) {
  __shared__ half_t hlds[16384];        // 32 KB: h as [kk][64 rows][32 halves]
  __shared__ half_t wlds[12288];        // 24 KB: 3 x 8 KB weight ring

  int bid = blockIdx.x;
  int mode, blk;
  const half_t* W; const float* bias; const float* wh; const float* b2p; float* outp;
  if (bid < 1024)      { mode = 1; blk = bid;        W = Wp + 262144; bias = pit_b; wh = pit_w; b2p = pit_b2; outp = out2; }
  else if (bid < 2048) { mode = 2; blk = bid - 1024; W = Wp + 524288; bias = en_b;  wh = en_w;  b2p = en_b2;  outp = out3; }
  else                 { mode = 0; blk = bid - 2048; W = Wp;          bias = dur_b; wh = dur_w; b2p = dur_b2; outp = out1; }

  int tid = threadIdx.x;
  int wv = tid >> 6, lane = tid & 63;
  int mi = lane & 15, qi = lane >> 4;
  int wrow0 = wv * 32;            // wave's exclusive 32 rows within block
  int brow0 = blk * 64;

  const char* Wb = (const char*)W;          // chunk c at byte offset c*8192

  // stage chunk c into ring slot s; wave wv copies its contiguous 4 KB half.
#define STAGE(c, s)                                                          \
  {                                                                          \
    const char* gsrc = Wb + (size_t)(c) * 8192 + wv * 4096 + lane * 16;      \
    char* ldst = (char*)wlds + (s) * 8192 + wv * 4096;                       \
    stage16(gsrc,        ldst);                                              \
    stage16(gsrc + 1024, ldst + 1024);                                       \
    stage16(gsrc + 2048, ldst + 2048);                                       \
    stage16(gsrc + 3072, ldst + 3072);                                       \
  }

  // ---- issue chunk 0/1 stages first: they land under the h-gather ----
  STAGE(0, 0);
  STAGE(1, 1);

  // ---- stage this wave's 32 input rows (f16) into LDS [kk][row][32] ----
  // lane writes features f=lane*4..+3 of row rl at
  //   hlds[(lane>>3)*2048 + rl*32 + (lane&7)*4]
  if (mode == 0) {
    for (int it = 0; it < 32; ++it) {
      int rl = wrow0 + it;
      const float4 xv = *(const float4*)&x[(size_t)(brow0 + rl) * H_ + lane * 4];
      half4 h4;
      h4[0] = (half_t)xv.x; h4[1] = (half_t)xv.y;
      h4[2] = (half_t)xv.z; h4[3] = (half_t)xv.w;
      *(half4*)&hlds[(lane >> 3) * 2048 + rl * 32 + (lane & 7) * 4] = h4;
    }
  } else {
    int b = brow0 >> 11;          // 64 | 2048 frames per batch
    int m0 = brow0 & (L_ - 1);
    int ml = mlw[b];
    for (int it = 0; it < 32; ++it) {
      int rl = wrow0 + it;
      int m = m0 + rl;
      int g = b * L_ + m;
      float4 xv = {0.f, 0.f, 0.f, 0.f};
      if (m < ml) {
        int ir = idx_ws[g];
        xv = *(const float4*)&x[((size_t)(b * T_ + ir)) * H_ + lane * 4];
      }
      if (mode == 1) {
        // fused out0 = xe + pemb[pi] + eemb[ei]
        const float4 pv = *(const float4*)&pemb[(size_t)pi_ws[g] * H_ + lane * 4];
        const float4 ev = *(const float4*)&eemb[(size_t)ei_ws[g] * H_ + lane * 4];
        floatx4 o;
        o[0] = xv.x + pv.x + ev.x;
        o[1] = xv.y + pv.y + ev.y;
        o[2] = xv.z + pv.z + ev.z;
        o[3] = xv.w + pv.w + ev.w;
        __builtin_nontemporal_store(o, (floatx4*)&out0[(size_t)g * H_ + lane * 4]);
      }
      half4 h4;
      h4[0] = (half_t)xv.x; h4[1] = (half_t)xv.y;
      h4[2] = (half_t)xv.z; h4[3] = (half_t)xv.w;
      *(half4*)&hlds[(lane >> 3) * 2048 + rl * 32 + (lane & 7) * 4] = h4;
    }
  }
  __syncthreads();   // h visible; chunks 0,1 landed (full drain, once)

  half8 hf[2][8];    // [mt][kk] : h[wrow0+mt*16+mi][kk*32+qi*8 .. +7]
  float p0 = 0.f, p1 = 0.f;   // head partials (layer 3)
  int sl = 0;                 // ring slot of current chunk

#pragma unroll 1
  for (int c = 0; c < 64; ++c) {
    int layer = c >> 4, nt = c & 15;

    if (nt == 0) {
      // (re)load this wave's 32 rows' fragments (1024B-contiguous reads)
#pragma unroll
      for (int mt = 0; mt < 2; ++mt)
#pragma unroll
        for (int kk = 0; kk < 8; ++kk)
          hf[mt][kk] = *(const half8*)&hlds[kk * 2048 + (wrow0 + mt * 16 + mi) * 32 + qi * 8];
    }

    // weights for chunk c from ring slot sl (1024B-contiguous per kk)
    const half_t* wb = &wlds[sl * 4096];
    half8 w[8];
#pragma unroll
    for (int kk = 0; kk < 8; ++kk)
      w[kk] = *(const half8*)&wb[kk * 512 + lane * 8];

    // my LDS reads done (so ring slot overwrite next iter is safe for me)
    asm volatile("s_waitcnt lgkmcnt(0)" ::: "memory");
    __builtin_amdgcn_sched_barrier(0);
    // stage chunk c+2 into the slot read two iters ago; counted wait on c+1
    int sl2 = sl + 2; if (sl2 >= 3) sl2 -= 3;
    if (c < 62) {
      STAGE(c + 2, sl2);
      asm volatile("s_waitcnt vmcnt(4)" ::: "memory");
    } else {
      asm volatile("s_waitcnt vmcnt(0)" ::: "memory");
    }
    __builtin_amdgcn_sched_barrier(0);
    __builtin_amdgcn_s_barrier();   // all waves: read c done, chunk c+1 landed
    __builtin_amdgcn_sched_barrier(0);

    // 16 MFMA, 4 independent 4-deep chains
    floatx4 a0l = {0.f, 0.f, 0.f, 0.f}, a0h = a0l, a1l = a0l, a1h = a0l;
#pragma unroll
    for (int kk = 0; kk < 4; ++kk) {
      a0l = __builtin_amdgcn_mfma_f32_16x16x32_f16(w[kk], hf[0][kk], a0l, 0, 0, 0);
      a1l = __builtin_amdgcn_mfma_f32_16x16x32_f16(w[kk], hf[1][kk], a1l, 0, 0, 0);
    }
#pragma unroll
    for (int kk = 4; kk < 8; ++kk) {
      a0h = __builtin_amdgcn_mfma_f32_16x16x32_f16(w[kk], hf[0][kk], a0h, 0, 0, 0);
      a1h = __builtin_amdgcn_mfma_f32_16x16x32_f16(w[kk], hf[1][kk], a1h, 0, 0, 0);
    }

    const float* bl = bias + layer * 256;
    const float4 bv = *(const float4*)&bl[nt * 16 + qi * 4];
    float v00 = fmaxf(a0l[0] + a0h[0] + bv.x, 0.f);
    float v01 = fmaxf(a0l[1] + a0h[1] + bv.y, 0.f);
    float v02 = fmaxf(a0l[2] + a0h[2] + bv.z, 0.f);
    float v03 = fmaxf(a0l[3] + a0h[3] + bv.w, 0.f);
    float v10 = fmaxf(a1l[0] + a1h[0] + bv.x, 0.f);
    float v11 = fmaxf(a1l[1] + a1h[1] + bv.y, 0.f);
    float v12 = fmaxf(a1l[2] + a1h[2] + bv.z, 0.f);
    float v13 = fmaxf(a1l[3] + a1h[3] + bv.w, 0.f);

    if (layer < 3) {
      // h' back to LDS (f16), wave-exclusive rows
      half4 h40, h41;
      h40[0] = (half_t)v00; h40[1] = (half_t)v01; h40[2] = (half_t)v02; h40[3] = (half_t)v03;
      h41[0] = (half_t)v10; h41[1] = (half_t)v11; h41[2] = (half_t)v12; h41[3] = (half_t)v13;
      int base = (nt >> 1) * 2048 + (nt & 1) * 16 + qi * 4;
      *(half4*)&hlds[base + (wrow0 + mi) * 32] = h40;
      *(half4*)&hlds[base + (wrow0 + 16 + mi) * 32] = h41;
    } else {
      // fused head: p += relu(h') . w  (f32)
      const float4 wv4 = *(const float4*)&wh[nt * 16 + qi * 4];
      p0 += v00 * wv4.x + v01 * wv4.y + v02 * wv4.z + v03 * wv4.w;
      p1 += v10 * wv4.x + v11 * wv4.y + v12 * wv4.z + v13 * wv4.w;
    }

    sl = (sl == 2) ? 0 : sl + 1;
  }

  // ---- head finalize: reduce partials across the 4 qi lanes ----
  p0 += __shfl_xor(p0, 16); p0 += __shfl_xor(p0, 32);
  p1 += __shfl_xor(p1, 16); p1 += __shfl_xor(p1, 32);
  if (qi < 2) {
    float sum = (qi == 0) ? p0 : p1;
    int row = brow0 + wrow0 + ((qi == 0) ? mi : 16 + mi);
    float d = sum + b2p[0];
    if (mode == 0) {
      if (src_mask[row]) d = 0.f;
      float s2 = src_seq[(size_t)row * 3 + 2];
      outp[row] = (tanhf(d) + 1.0f) * s2;
    } else {
      int b = row >> 11;
      int m = row & (L_ - 1);
      float v = (m >= mlw[b]) ? 0.f : d;
      outp[row] = (mode == 1) ? fmaxf(v, 0.f) : v;
    }
  }
#undef STAGE
}

extern "C" void kernel_launch(void* const* d_in, const int* in_sizes, int n_in,
                              void* d_out, int out_size, void* d_ws, size_t ws_size,
                              hipStream_t stream) {
  const float* x        = (const float*)d_in[0];
  const float* src_seq  = (const float*)d_in[1];
  const int*   durt     = (const int*)d_in[2];
  const float* pitcht   = (const float*)d_in[3];
  const float* energyt  = (const float*)d_in[4];
  const unsigned char* src_mask = (const unsigned char*)d_in[5];
  const float* dur_W  = (const float*)d_in[7];
  const float* dur_b  = (const float*)d_in[8];
  const float* dur_w  = (const float*)d_in[9];
  const float* dur_b2 = (const float*)d_in[10];
  const float* pit_W  = (const float*)d_in[11];
  const float* pit_b  = (const float*)d_in[12];
  const float* pit_w  = (const float*)d_in[13];
  const float* pit_b2 = (const float*)d_in[14];
  const float* en_W   = (const float*)d_in[15];
  const float* en_b   = (const float*)d_in[16];
  const float* en_w   = (const float*)d_in[17];
  const float* en_b2  = (const float*)d_in[18];
  const float* pemb   = (const float*)d_in[19];
  const float* eemb   = (const float*)d_in[20];

  float* out0 = (float*)d_out;              // [32,2048,256]
  float* out1 = out0 + 16777216;            // [32,512]   log_duration
  float* out2 = out1 + 16384;               // [32,2048]  pitch_prediction
  float* out3 = out2 + 65536;               // [32,2048]  energy_prediction
  float* out4 = out3 + 65536;               // [32]       mel_len (as float)
  float* out5 = out4 + 32;                  // [32,2048]  mel_mask (0/1 float)

  int* idx_ws = (int*)d_ws;                 // 65536 ints
  int* pi_ws  = idx_ws + 65536;             // 65536 ints
  int* ei_ws  = pi_ws + 65536;              // 65536 ints
  int* ml_ws  = ei_ws + 65536;              // 32 ints
  half_t* Wp  = (half_t*)((char*)d_ws + 786560);  // 786432 halves, 16B aligned

  setup_kernel<<<dim3(512), dim3(256), 0, stream>>>(
      durt, pitcht, energyt, dur_W, pit_W, en_W, Wp,
      idx_ws, pi_ws, ei_ws, ml_ws, out4, out5);
  predictor_kernel<<<dim3(2304), dim3(128), 0, stream>>>(
      x, Wp,
      dur_b, dur_w, dur_b2,
      pit_b, pit_w, pit_b2,
      en_b, en_w, en_b2,
      idx_ws, pi_ws, ei_ws, ml_ws, src_seq, src_mask, pemb, eemb,
      out0, out1, out2, out3);
}

// Round 9
// 245.165 us; speedup vs baseline: 1.4209x; 1.4209x over previous
//
#include <hip/hip_runtime.h>

typedef _Float16 half_t;
typedef _Float16 half4 __attribute__((ext_vector_type(4)));
typedef _Float16 half8 __attribute__((ext_vector_type(8)));
typedef float floatx4 __attribute__((ext_vector_type(4)));

#define HST 264            // LDS row stride in halves: 256 + 8 pad
#define B_ 32
#define T_ 512
#define H_ 256
#define L_ 2048

// ------------------------------------------------------------------
// Fused setup: blocks [0,128) = meta (scan/searchsorted/bucket idx),
// blocks [128,512) = weight prep fp32 -> f16 MFMA fragment layout.
// Frag id t = ((pred*4+layer)*8 + kk)*16 + nt ; lane l holds 8 halves:
//   W[kk*32 + (l>>4)*8 + j][nt*16 + (l&15)]
// ------------------------------------------------------------------
__global__ __launch_bounds__(256) void setup_kernel(
    const int* __restrict__ dur,
    const float* __restrict__ pitch_t,
    const float* __restrict__ energy_t,
    const float* __restrict__ dur_W,
    const float* __restrict__ pit_W,
    const float* __restrict__ en_W,
    half_t* __restrict__ Wp,
    int* __restrict__ idx_ws,
    int* __restrict__ pi_ws,
    int* __restrict__ ei_ws,
    int* __restrict__ ml_ws,
    float* __restrict__ out4,
    float* __restrict__ out5) {
  __shared__ int cum_l[T_];
  __shared__ int ml_s;
  int bid = blockIdx.x;
  int tid = threadIdx.x;

  if (bid >= 128) {
    // ---- weight prep ----
    int g = (bid - 128) * 256 + tid;          // [0, 98304)
    int lane = g & 63;
    int t = g >> 6;                            // [0, 1536)
    int nt = t & 15;
    int kk = (t >> 4) & 7;
    int layer = (t >> 7) & 3;
    int pred = t >> 9;
    const float* W = (pred == 0 ? dur_W : (pred == 1 ? pit_W : en_W)) + layer * 65536;
    int n = nt * 16 + (lane & 15);
    int k0 = kk * 32 + (lane >> 4) * 8;
    half8 o;
#pragma unroll
    for (int j = 0; j < 8; ++j) o[j] = (half_t)W[(k0 + j) * 256 + n];
    *(half8*)&Wp[(size_t)t * 512 + lane * 8] = o;
    return;
  }

  // ---- meta ----
  int b = bid >> 2;
  int chunk = bid & 3;
  if (tid < 64) {
    int l = tid;
    const int* dr = dur + b * T_;
    int v[8];
    int base = l * 8;
#pragma unroll
    for (int j = 0; j < 8; ++j) v[j] = dr[base + j];
#pragma unroll
    for (int j = 1; j < 8; ++j) v[j] += v[j - 1];
    int tot = v[7];
    int inc = tot;
    for (int d = 1; d < 64; d <<= 1) {
      int t = __shfl_up(inc, d);
      if (l >= d) inc += t;
    }
    int excl = inc - tot;
#pragma unroll
    for (int j = 0; j < 8; ++j) cum_l[base + j] = excl + v[j];
    if (l == 63) {
      int mel = min(inc, L_);
      ml_s = mel;
      if (chunk == 0) {
        ml_ws[b] = mel;
        out4[b] = (float)mel;
      }
    }
  }
  __syncthreads();
  int ml = ml_s;
#pragma unroll
  for (int j = 0; j < 2; ++j) {
    int m = chunk * 512 + j * 256 + tid;
    int lo = 0;
#pragma unroll
    for (int sh = 8; sh >= 0; --sh) {
      int c = lo + (1 << sh);
      if (c <= T_ && cum_l[c - 1] <= m) lo = c;
    }
    int idx = min(lo, T_ - 1);
    int g = b * L_ + m;
    idx_ws[g] = idx;
    pi_ws[g] = (int)ceilf(pitch_t[g] * 256.0f);
    ei_ws[g] = (int)ceilf(energy_t[g] * 256.0f);
    out5[g] = (m >= ml) ? 1.0f : 0.0f;
  }
}

// ------------------------------------------------------------------
// Fused 4-layer MLP + head — ROUND-0 PROVEN STRUCTURE, verbatim.
// blocks [0,1024): pitch  [1024,2048): energy  [2048,2304): duration.
// Block = 128 threads (2 waves) owning 64 rows; each wave owns 32
// rows EXCLUSIVELY -> zero __syncthreads (in-place LDS update safe:
// the wave reads its rows' fragments into registers before writing).
// Each wave loops ALL 16 nt tiles with a W ping-pong (distance-1).
// Only change vs round-0: pitch-mode staging also emits
// out0 = xe + pemb + eemb (fused out0_kernel; same gather).
// ------------------------------------------------------------------
__global__ __launch_bounds__(128) void predictor_kernel(
    const float* __restrict__ x,
    const half_t* __restrict__ Wp,
    const float* __restrict__ dur_b, const float* __restrict__ dur_w, const float* __restrict__ dur_b2,
    const float* __restrict__ pit_b, const float* __restrict__ pit_w, const float* __restrict__ pit_b2,
    const float* __restrict__ en_b,  const float* __restrict__ en_w,  const float* __restrict__ en_b2,
    const int* __restrict__ idx_ws, const int* __restrict__ pi_ws, const int* __restrict__ ei_ws,
    const int* __restrict__ mlw,
    const float* __restrict__ src_seq, const unsigned char* __restrict__ src_mask,
    const float* __restrict__ pemb, const float* __restrict__ eemb,
    float* __restrict__ out0, float* __restrict__ out1,
    float* __restrict__ out2, float* __restrict__ out3) {
  __shared__ half_t hlds[64 * HST];
  int bid = blockIdx.x;
  int mode, blk;
  const half_t* W; const float* bias; const float* wh; const float* b2p; float* outp;
  if (bid < 1024)      { mode = 1; blk = bid;        W = Wp + 262144; bias = pit_b; wh = pit_w; b2p = pit_b2; outp = out2; }
  else if (bid < 2048) { mode = 2; blk = bid - 1024; W = Wp + 524288; bias = en_b;  wh = en_w;  b2p = en_b2;  outp = out3; }
  else                 { mode = 0; blk = bid - 2048; W = Wp;          bias = dur_b; wh = dur_w; b2p = dur_b2; outp = out1; }

  int tid = threadIdx.x;
  int wv = tid >> 6, lane = tid & 63;
  int mi = lane & 15, qi = lane >> 4;
  int wrow0 = wv * 32;            // wave's exclusive 32 rows within block
  int brow0 = blk * 64;

  // ---- stage this wave's 32 input rows (f16) into LDS ----
  if (mode == 0) {
    for (int it = 0; it < 32; ++it) {
      int rl = wrow0 + it;
      const float4 xv = *(const float4*)&x[(size_t)(brow0 + rl) * H_ + lane * 4];
      half4 h4;
      h4[0] = (half_t)xv.x; h4[1] = (half_t)xv.y;
      h4[2] = (half_t)xv.z; h4[3] = (half_t)xv.w;
      *(half4*)&hlds[rl * HST + lane * 4] = h4;
    }
  } else {
    int b = brow0 >> 11;          // 64 | 2048 frames per batch
    int m0 = brow0 & (L_ - 1);
    int ml = mlw[b];
    for (int it = 0; it < 32; ++it) {
      int rl = wrow0 + it;
      int m = m0 + rl;
      int g = b * L_ + m;
      float4 xv = {0.f, 0.f, 0.f, 0.f};
      if (m < ml) {
        int ir = idx_ws[g];
        xv = *(const float4*)&x[((size_t)(b * T_ + ir)) * H_ + lane * 4];
      }
      if (mode == 1) {
        // fused out0 = xe + pemb[pi] + eemb[ei]
        const float4 pv = *(const float4*)&pemb[(size_t)pi_ws[g] * H_ + lane * 4];
        const float4 ev = *(const float4*)&eemb[(size_t)ei_ws[g] * H_ + lane * 4];
        floatx4 o;
        o[0] = xv.x + pv.x + ev.x;
        o[1] = xv.y + pv.y + ev.y;
        o[2] = xv.z + pv.z + ev.z;
        o[3] = xv.w + pv.w + ev.w;
        __builtin_nontemporal_store(o, (floatx4*)&out0[(size_t)g * H_ + lane * 4]);
      }
      half4 h4;
      h4[0] = (half_t)xv.x; h4[1] = (half_t)xv.y;
      h4[2] = (half_t)xv.z; h4[3] = (half_t)xv.w;
      *(half4*)&hlds[rl * HST + lane * 4] = h4;
    }
  }
  // no barrier: wave-exclusive rows

  // ---- 4 layers: h = relu(h @ W + b), in-place per wave ----
#pragma unroll 1
  for (int layer = 0; layer < 4; ++layer) {
    // wave's 32 rows' fragments into registers (64 VGPRs)
    half8 hf[2][8];   // [mt][kk] : h[wrow0+mt*16+mi][kk*32+qi*8 .. +7]
#pragma unroll
    for (int mt = 0; mt < 2; ++mt)
#pragma unroll
      for (int kk = 0; kk < 8; ++kk)
        hf[mt][kk] = *(const half8*)&hlds[(wrow0 + mt * 16 + mi) * HST + kk * 32 + qi * 8];

    const half_t* wl = W + (size_t)layer * 65536;
    const float* bl = bias + layer * 256;
    half8 wA[8], wB[8];
    float4 bA, bB;
#pragma unroll
    for (int kk = 0; kk < 8; ++kk)
      wA[kk] = *(const half8*)&wl[(size_t)(kk * 16 + 0) * 512 + lane * 8];
    bA = *(const float4*)&bl[0 * 16 + qi * 4];

#pragma unroll
    for (int ntp = 0; ntp < 8; ++ntp) {
      int nt0 = ntp * 2;
      // prefetch nt0+1 while computing nt0
#pragma unroll
      for (int kk = 0; kk < 8; ++kk)
        wB[kk] = *(const half8*)&wl[(size_t)(kk * 16 + nt0 + 1) * 512 + lane * 8];
      bB = *(const float4*)&bl[(nt0 + 1) * 16 + qi * 4];
      {
        floatx4 acc0 = {bA.x, bA.y, bA.z, bA.w};
        floatx4 acc1 = {bA.x, bA.y, bA.z, bA.w};
#pragma unroll
        for (int kk = 0; kk < 8; ++kk) {
          acc0 = __builtin_amdgcn_mfma_f32_16x16x32_f16(wA[kk], hf[0][kk], acc0, 0, 0, 0);
          acc1 = __builtin_amdgcn_mfma_f32_16x16x32_f16(wA[kk], hf[1][kk], acc1, 0, 0, 0);
        }
        int colbase = nt0 * 16 + qi * 4;
        half4 h40, h41;
        h40[0] = (half_t)fmaxf(acc0[0], 0.f); h40[1] = (half_t)fmaxf(acc0[1], 0.f);
        h40[2] = (half_t)fmaxf(acc0[2], 0.f); h40[3] = (half_t)fmaxf(acc0[3], 0.f);
        h41[0] = (half_t)fmaxf(acc1[0], 0.f); h41[1] = (half_t)fmaxf(acc1[1], 0.f);
        h41[2] = (half_t)fmaxf(acc1[2], 0.f); h41[3] = (half_t)fmaxf(acc1[3], 0.f);
        *(half4*)&hlds[(wrow0 + mi) * HST + colbase] = h40;
        *(half4*)&hlds[(wrow0 + 16 + mi) * HST + colbase] = h41;
      }
      // prefetch nt0+2 while computing nt0+1
      if (ntp < 7) {
#pragma unroll
        for (int kk = 0; kk < 8; ++kk)
          wA[kk] = *(const half8*)&wl[(size_t)(kk * 16 + nt0 + 2) * 512 + lane * 8];
        bA = *(const float4*)&bl[(nt0 + 2) * 16 + qi * 4];
      }
      {
        floatx4 acc0 = {bB.x, bB.y, bB.z, bB.w};
        floatx4 acc1 = {bB.x, bB.y, bB.z, bB.w};
#pragma unroll
        for (int kk = 0; kk < 8; ++kk) {
          acc0 = __builtin_amdgcn_mfma_f32_16x16x32_f16(wB[kk], hf[0][kk], acc0, 0, 0, 0);
          acc1 = __builtin_amdgcn_mfma_f32_16x16x32_f16(wB[kk], hf[1][kk], acc1, 0, 0, 0);
        }
        int colbase = (nt0 + 1) * 16 + qi * 4;
        half4 h40, h41;
        h40[0] = (half_t)fmaxf(acc0[0], 0.f); h40[1] = (half_t)fmaxf(acc0[1], 0.f);
        h40[2] = (half_t)fmaxf(acc0[2], 0.f); h40[3] = (half_t)fmaxf(acc0[3], 0.f);
        h41[0] = (half_t)fmaxf(acc1[0], 0.f); h41[1] = (half_t)fmaxf(acc1[1], 0.f);
        h41[2] = (half_t)fmaxf(acc1[2], 0.f); h41[3] = (half_t)fmaxf(acc1[3], 0.f);
        *(half4*)&hlds[(wrow0 + mi) * HST + colbase] = h40;
        *(half4*)&hlds[(wrow0 + 16 + mi) * HST + colbase] = h41;
      }
    }
  }

  // ---- head: out = h . w + b2, per-mode epilogue. 2 lanes per row ----
  {
    int r = lane >> 1, hf2 = lane & 1;
    int rl = wrow0 + r;
    float sum = 0.f;
    const half_t* hrow = &hlds[rl * HST + hf2 * 128];
    const float* whp = wh + hf2 * 128;
#pragma unroll
    for (int j = 0; j < 16; ++j) {
      half8 hv = *(const half8*)&hrow[j * 8];
#pragma unroll
      for (int u = 0; u < 8; ++u) sum += (float)hv[u] * whp[j * 8 + u];
    }
    sum += __shfl_xor(sum, 1);
    if (hf2 == 0) {
      int row = brow0 + rl;
      float d = sum + b2p[0];
      if (mode == 0) {
        if (src_mask[row]) d = 0.f;
        float s2 = src_seq[(size_t)row * 3 + 2];
        outp[row] = (tanhf(d) + 1.0f) * s2;
      } else {
        int b = row >> 11;
        int m = row & (L_ - 1);
        float v = (m >= mlw[b]) ? 0.f : d;
        outp[row] = (mode == 1) ? fmaxf(v, 0.f) : v;
      }
    }
  }
}

extern "C" void kernel_launch(void* const* d_in, const int* in_sizes, int n_in,
                              void* d_out, int out_size, void* d_ws, size_t ws_size,
                              hipStream_t stream) {
  const float* x        = (const float*)d_in[0];
  const float* src_seq  = (const float*)d_in[1];
  const int*   durt     = (const int*)d_in[2];
  const float* pitcht   = (const float*)d_in[3];
  const float* energyt  = (const float*)d_in[4];
  const unsigned char* src_mask = (const unsigned char*)d_in[5];
  const float* dur_W  = (const float*)d_in[7];
  const float* dur_b  = (const float*)d_in[8];
  const float* dur_w  = (const float*)d_in[9];
  const float* dur_b2 = (const float*)d_in[10];
  const float* pit_W  = (const float*)d_in[11];
  const float* pit_b  = (const float*)d_in[12];
  const float* pit_w  = (const float*)d_in[13];
  const float* pit_b2 = (const float*)d_in[14];
  const float* en_W   = (const float*)d_in[15];
  const float* en_b   = (const float*)d_in[16];
  const float* en_w   = (const float*)d_in[17];
  const float* en_b2  = (const float*)d_in[18];
  const float* pemb   = (const float*)d_in[19];
  const float* eemb   = (const float*)d_in[20];

  float* out0 = (float*)d_out;              // [32,2048,256]
  float* out1 = out0 + 16777216;            // [32,512]   log_duration
  float* out2 = out1 + 16384;               // [32,2048]  pitch_prediction
  float* out3 = out2 + 65536;               // [32,2048]  energy_prediction
  float* out4 = out3 + 65536;               // [32]       mel_len (as float)
  float* out5 = out4 + 32;                  // [32,2048]  mel_mask (0/1 float)

  int* idx_ws = (int*)d_ws;                 // 65536 ints
  int* pi_ws  = idx_ws + 65536;             // 65536 ints
  int* ei_ws  = pi_ws + 65536;              // 65536 ints
  int* ml_ws  = ei_ws + 65536;              // 32 ints
  half_t* Wp  = (half_t*)((char*)d_ws + 786560);  // 786432 halves, 16B aligned

  setup_kernel<<<dim3(512), dim3(256), 0, stream>>>(
      durt, pitcht, energyt, dur_W, pit_W, en_W, Wp,
      idx_ws, pi_ws, ei_ws, ml_ws, out4, out5);
  predictor_kernel<<<dim3(2304), dim3(128), 0, stream>>>(
      x, Wp,
      dur_b, dur_w, dur_b2,
      pit_b, pit_w, pit_b2,
      en_b, en_w, en_b2,
      idx_ws, pi_ws, ei_ws, ml_ws, src_seq, src_mask, pemb, eemb,
      out0, out1, out2, out3);
}